// Round 8
// baseline (77.159 us; speedup 1.0000x reference)
//
#include <hip/hip_runtime.h>
#include <cstdint>

typedef short bf16x8 __attribute__((ext_vector_type(8)));
typedef float f32x4 __attribute__((ext_vector_type(4)));

#define NO 8
#define NT 4
#define ND 256
#define NH1 64
#define NH2 32
#define BM 32
#define BNEPS 1e-5f

__device__ __forceinline__ unsigned bfpack2(float a, float b) {
    unsigned ua = __float_as_uint(a), ub = __float_as_uint(b);
    ua = (ua + 0x7FFFu + ((ua >> 16) & 1u)) >> 16;
    ub = (ub + 0x7FFFu + ((ub >> 16) & 1u)) >> 16;
    return ua | (ub << 16);
}

// ws layout (bytes):
//   [0,64): int cnt[4] @0, cursor[4] @16  (zeroed by memset)
//   rperm[(B+128)]: padded slot -> row id (-1 holes; memset 0xFF)
//   iperm[B]: row id -> padded slot
//   W1T (1 MB), W2T (128 KB), P1 (24 KB), P2 (12 KB)
//   Xs: (B+128) rows x 512 B bf16, pre-swizzled (byte ^= (slot&7)<<4)

__global__ void k_hist_prep(const int* __restrict__ trt, int* __restrict__ ws, int B,
                            const float* __restrict__ W1, const float* __restrict__ W2,
                            const float* __restrict__ b1, const float* __restrict__ g1,
                            const float* __restrict__ be1, const float* __restrict__ m1,
                            const float* __restrict__ v1,
                            const float* __restrict__ b2, const float* __restrict__ g2,
                            const float* __restrict__ be2, const float* __restrict__ m2,
                            const float* __restrict__ v2, const float* __restrict__ W3,
                            unsigned* __restrict__ W1T4, unsigned* __restrict__ W2T4,
                            float* __restrict__ P1, float* __restrict__ P2) {
    const int bid = blockIdx.x, tid = threadIdx.x;
    if (bid < 256) {                                      // ---- histogram ----
        __shared__ int loc[NT];
        if (tid < NT) loc[tid] = 0;
        __syncthreads();
        const int i = bid * 256 + tid;
        if (i < B) atomicAdd(&loc[trt[i] & 3], 1);
        __syncthreads();
        if (tid < NT) atomicAdd(&ws[tid], loc[tid]);
    } else if (bid < 512) {                               // ---- W1T frags ----
        const int gi = (bid - 256) * 256 + tid;           // 65536
        const int lane = gi & 63, nt = (gi >> 6) & 31, c = (gi >> 11) & 7, t = gi >> 14;
        const int n16 = lane & 15, kg = lane >> 4;
        const int n = nt * 16 + n16, o = n >> 6, h = n & 63;
        const int k0 = c * 32 + kg * 8;
        const float* src = W1 + ((size_t)(o * NT + t) * ND + k0) * NH1 + h;
        float v[8];
#pragma unroll
        for (int j = 0; j < 8; ++j) v[j] = src[(size_t)j * NH1];
        uint4 q;
        q.x = bfpack2(v[0], v[1]); q.y = bfpack2(v[2], v[3]);
        q.z = bfpack2(v[4], v[5]); q.w = bfpack2(v[6], v[7]);
        ((uint4*)W1T4)[gi] = q;
    } else if (bid < 544) {                               // ---- W2T frags ----
        const int gi = (bid - 512) * 256 + tid;           // 8192
        const int m16 = gi & 15, kg = (gi >> 4) & 3, ks = (gi >> 6) & 1,
                  kt = (gi >> 7) & 1, o = (gi >> 8) & 7, t = gi >> 11;
        const int k2 = kt * 16 + m16, hb = ks * 32 + kg * 8;
        const float* src = W2 + ((size_t)(o * NT + t) * NH1 + hb) * NH2 + k2;
        float v[8];
#pragma unroll
        for (int j = 0; j < 8; ++j) v[j] = src[(size_t)j * NH2];
        uint4 q;
        q.x = bfpack2(v[0], v[1]); q.y = bfpack2(v[2], v[3]);
        q.z = bfpack2(v[4], v[5]); q.w = bfpack2(v[6], v[7]);
        ((uint4*)W2T4)[gi] = q;
    } else if (bid < 552) {                               // ---- P1: BN1 fold ----
        const int gi = (bid - 544) * 256 + tid;           // 2048 = 4t x 512n
        const int t = gi >> 9, n = gi & 511;
        const int o = n >> 6, h = n & 63;
        const int idx = (o * NT + t) * NH1 + h;
        const float sc = g1[idx] * rsqrtf(v1[idx] + BNEPS);
        P1[gi] = sc;
        P1[2048 + gi] = be1[idx] - m1[idx] * sc;
        P1[4096 + gi] = b1[idx];
    } else {                                              // ---- P2: BN2+W3 fold ----
        const int gi = (bid - 552) * 256 + tid;           // 1024 = 4t x 256(o,k2)
        const int t = gi >> 8, q = gi & 255;
        const int o = q >> 5, k2 = q & 31;
        const int idx = (o * NT + t) * NH2 + k2;
        const float s = g2[idx] * rsqrtf(v2[idx] + BNEPS);
        const float w3 = W3[idx];
        P2[gi] = s * w3;
        P2[1024 + gi] = (be2[idx] - m2[idx] * s) * w3;
        P2[2048 + gi] = b2[idx];
    }
}

__global__ void k_scatter(const int* __restrict__ trt, int* __restrict__ ws,
                          int* __restrict__ rperm, int* __restrict__ iperm, int B) {
    __shared__ int loc[NT], gb[NT];
    const int tid = threadIdx.x;
    if (tid < NT) loc[tid] = 0;
    __syncthreads();
    const int i = blockIdx.x * blockDim.x + tid;
    int tt = 0, pos = 0;
    if (i < B) { tt = trt[i] & 3; pos = atomicAdd(&loc[tt], 1); }
    __syncthreads();
    if (tid < NT) {
        const int c0 = ws[0], c1 = ws[1], c2 = ws[2];
        const int q0 = (c0 + 31) & ~31, q1 = (c1 + 31) & ~31, q2 = (c2 + 31) & ~31;
        const int eb = tid == 0 ? 0 : tid == 1 ? q0 : tid == 2 ? q0 + q1 : q0 + q1 + q2;
        gb[tid] = eb + atomicAdd(&ws[4 + tid], loc[tid]);
    }
    __syncthreads();
    if (i < B) {
        const int p = gb[tt] + pos;       // padded slot
        rperm[p] = i;
        iperm[i] = p;
    }
}

// streaming permute: coalesced X read (row order) -> bf16 -> pre-swizzled Xs row
__global__ __launch_bounds__(256) void k_xcopy(const float* __restrict__ X,
                                               const int* __restrict__ iperm,
                                               char* __restrict__ Xs, int B) {
    const int w = threadIdx.x >> 6, l = threadIdx.x & 63;
    const int i0 = (blockIdx.x * 4 + w) * 32;
#pragma unroll 4
    for (int j = 0; j < 32; ++j) {
        const int i = i0 + j;
        if (i < B) {
            const int s = iperm[i];
            const float4 xv = *(const float4*)(X + (size_t)i * ND + l * 4);
            uint2 pk;
            pk.x = bfpack2(xv.x, xv.y);
            pk.y = bfpack2(xv.z, xv.w);
            *(uint2*)(Xs + (size_t)s * 512 + ((l * 8) ^ ((s & 7) << 4))) = pk;
        }
    }
}

// ---------------- fused 3-layer expert MLP ----------------
__global__ __launch_bounds__(256, 3) void k_main(
    const float* __restrict__ X, const int* __restrict__ ws, const int* __restrict__ rperm,
    const char* __restrict__ Xs, const int useXs,
    const char* __restrict__ W1T, const char* __restrict__ W2T,
    const float* __restrict__ P1, const float* __restrict__ P2,
    const float* __restrict__ pb3, float* __restrict__ out)
{
    const int c0 = ws[0], c1 = ws[1], c2 = ws[2], c3 = ws[3];
    const int q0 = (c0 + 31) & ~31, q1 = (c1 + 31) & ~31, q2 = (c2 + 31) & ~31;
    const int e0 = q0, e1 = q0 + q1, e2 = e1 + q2, e3 = e2 + ((c3 + 31) & ~31);
    const int m0 = blockIdx.x * BM;
    if (m0 >= e3) return;
    const int t = (m0 >= e0) + (m0 >= e1) + (m0 >= e2);

    const int tid = threadIdx.x;
    const int w = tid >> 6;
    const int l = tid & 63;

    // [0,16384): X tile [32 r][512 B] bf16 swizzled; after barrier: Hr [32 r][1024 B]
    __shared__ __align__(16) char LDS[32768];

    const int rid_o = rperm[m0 + (l & 31)];     // padded slot -> row (-1 = hole)

    if (useXs) {
        // contiguous 4 KB per wave from Xs (already bf16 + swizzled): linear LDS dest
        const size_t srow = (size_t)(m0 + w * 8) * 512 + (size_t)(l * 16);
#pragma unroll
        for (int u = 0; u < 4; ++u) {
            __builtin_amdgcn_global_load_lds(
                (const __attribute__((address_space(1))) void*)(Xs + srow + u * 1024),
                (__attribute__((address_space(3))) void*)(LDS + w * 4096 + l * 16 + u * 1024),
                16, 0, 0);
        }
    } else {
        // fallback: gather rows via rperm (R7 path)
#pragma unroll
        for (int j = 0; j < 8; ++j) {
            const int r = w * 8 + j;
            const int rr = __shfl(rid_o, r);
            const int rrow = rr < 0 ? 0 : rr;
            const float4 xv = *(const float4*)(X + (size_t)rrow * ND + l * 4);
            uint2 pk;
            pk.x = bfpack2(xv.x, xv.y);
            pk.y = bfpack2(xv.z, xv.w);
            *(uint2*)(LDS + r * 512 + ((l * 8) ^ ((r & 7) << 4))) = pk;
        }
    }

    f32x4 acc[8][2];
#pragma unroll
    for (int nt = 0; nt < 8; ++nt)
#pragma unroll
        for (int rt = 0; rt < 2; ++rt) acc[nt][rt] = (f32x4){0.f, 0.f, 0.f, 0.f};

    const char* W1Tt = W1T + (size_t)t * 262144;
    const char* W1Tw = W1Tt + (w * 8) * 1024 + l * 16;
    const int ln4 = (l >> 4) * 4;

    // chunk-0 W frags issued before the barrier
    bf16x8 aA[8], aB[8];
#pragma unroll
    for (int nt = 0; nt < 8; ++nt)
        aA[nt] = *(const bf16x8*)(W1Tw + nt * 1024);

    __syncthreads();

    // ---- K-loop: chunk c+1 W frags issued before chunk c MFMAs ----
#pragma unroll
    for (int c = 0; c < 8; ++c) {
        if (c < 7) {
            if ((c & 1) == 0) {
#pragma unroll
                for (int nt = 0; nt < 8; ++nt)
                    aB[nt] = *(const bf16x8*)(W1Tw + (c + 1) * 32768 + nt * 1024);
            } else {
#pragma unroll
                for (int nt = 0; nt < 8; ++nt)
                    aA[nt] = *(const bf16x8*)(W1Tw + (c + 1) * 32768 + nt * 1024);
            }
        }
#pragma unroll
        for (int rt = 0; rt < 2; ++rt) {
            const int r = rt * 16 + (l & 15);
            const bf16x8 bX = *(const bf16x8*)(LDS + r * 512 +
                                               ((c * 64 + (l >> 4) * 16) ^ ((r & 7) << 4)));
            if ((c & 1) == 0) {
#pragma unroll
                for (int nt = 0; nt < 8; ++nt)
                    acc[nt][rt] = __builtin_amdgcn_mfma_f32_16x16x32_bf16(aA[nt], bX, acc[nt][rt], 0, 0, 0);
            } else {
#pragma unroll
                for (int nt = 0; nt < 8; ++nt)
                    acc[nt][rt] = __builtin_amdgcn_mfma_f32_16x16x32_bf16(aB[nt], bX, acc[nt][rt], 0, 0, 0);
            }
        }
    }
    __syncthreads();     // X reads done; LDS becomes Hr

    // ---- epilogue L1: bias+ReLU+BN1 (pre-folded), bf16 swizzled Hr ----
#pragma unroll
    for (int nt = 0; nt < 8; ++nt) {
        const int n0 = (w * 8 + nt) * 16 + ln4;
        const int p = t * 512 + n0;
        const float4 scv = *(const float4*)(P1 + p);
        const float4 shv = *(const float4*)(P1 + 2048 + p);
        const float4 bbv = *(const float4*)(P1 + 4096 + p);
#pragma unroll
        for (int rt = 0; rt < 2; ++rt) {
            const int r = rt * 16 + (l & 15);
            const f32x4 a = acc[nt][rt];
            const float z0 = fmaf(fmaxf(a[0] + bbv.x, 0.f), scv.x, shv.x);
            const float z1 = fmaf(fmaxf(a[1] + bbv.y, 0.f), scv.y, shv.y);
            const float z2 = fmaf(fmaxf(a[2] + bbv.z, 0.f), scv.z, shv.z);
            const float z3 = fmaf(fmaxf(a[3] + bbv.w, 0.f), scv.w, shv.w);
            uint2 pk;
            pk.x = bfpack2(z0, z1); pk.y = bfpack2(z2, z3);
            *(uint2*)(LDS + r * 1024 + (((unsigned)(n0 * 2)) ^ (unsigned)((r & 7) << 4))) = pk;
        }
    }
    // each wave reads only its own Hr columns -> no barrier needed

    // ---- layer 2: MFMA over the wave's 2 outcomes ----
    bf16x8 aW[2][2][2];   // [oo][kt][ks]
#pragma unroll
    for (int oo = 0; oo < 2; ++oo) {
        const int o = w * 2 + oo;
#pragma unroll
        for (int kt = 0; kt < 2; ++kt)
#pragma unroll
            for (int ks = 0; ks < 2; ++ks)
                aW[oo][kt][ks] = *(const bf16x8*)(W2T +
                    ((((size_t)t * NO + o) * 2 + kt) * 2 + ks) * 1024 + l * 16);
    }
    f32x4 acc2[2][2][2];  // [oo][kt][rt2]
#pragma unroll
    for (int oo = 0; oo < 2; ++oo)
#pragma unroll
        for (int kt = 0; kt < 2; ++kt)
#pragma unroll
            for (int rt2 = 0; rt2 < 2; ++rt2) acc2[oo][kt][rt2] = (f32x4){0.f, 0.f, 0.f, 0.f};

#pragma unroll
    for (int rt2 = 0; rt2 < 2; ++rt2) {
        const int r = rt2 * 16 + (l & 15);
        const unsigned swz = (unsigned)((r & 7) << 4);
#pragma unroll
        for (int ks = 0; ks < 2; ++ks) {
            const int nb = ks * 32 + (l >> 4) * 8;
#pragma unroll
            for (int oo = 0; oo < 2; ++oo) {
                const int n8 = (w * 2 + oo) * 64 + nb;
                const bf16x8 bH = *(const bf16x8*)(LDS + r * 1024 + (((unsigned)(n8 * 2)) ^ swz));
#pragma unroll
                for (int kt = 0; kt < 2; ++kt)
                    acc2[oo][kt][rt2] = __builtin_amdgcn_mfma_f32_16x16x32_bf16(aW[oo][kt][ks], bH, acc2[oo][kt][rt2], 0, 0, 0);
            }
        }
    }

    // ---- BN2 + ReLU + layer3 dot (pre-folded), reduce over k-lane-groups ----
    float p[2][2];
#pragma unroll
    for (int oo = 0; oo < 2; ++oo)
#pragma unroll
        for (int rt2 = 0; rt2 < 2; ++rt2) p[oo][rt2] = 0.f;

#pragma unroll
    for (int oo = 0; oo < 2; ++oo) {
        const int o = w * 2 + oo;
#pragma unroll
        for (int kt = 0; kt < 2; ++kt) {
            const int q = o * 32 + kt * 16 + ln4;
            const int p3 = t * 256 + q;
            const float4 A3 = *(const float4*)(P2 + p3);
            const float4 C3 = *(const float4*)(P2 + 1024 + p3);
            const float4 bb = *(const float4*)(P2 + 2048 + p3);
#pragma unroll
            for (int rt2 = 0; rt2 < 2; ++rt2) {
                const f32x4 a = acc2[oo][kt][rt2];
                float s = fmaf(fmaxf(a[0] + bb.x, 0.f), A3.x, C3.x);
                s = fmaf(fmaxf(a[1] + bb.y, 0.f), A3.y, s + C3.y);
                s = fmaf(fmaxf(a[2] + bb.z, 0.f), A3.z, s + C3.z);
                s = fmaf(fmaxf(a[3] + bb.w, 0.f), A3.w, s + C3.w);
                p[oo][rt2] += s;
            }
        }
    }
#pragma unroll
    for (int oo = 0; oo < 2; ++oo)
#pragma unroll
        for (int rt2 = 0; rt2 < 2; ++rt2) {
            float v = p[oo][rt2];
            v += __shfl_xor(v, 16);
            v += __shfl_xor(v, 32);
            p[oo][rt2] = v;
        }

    const int oo_s = l >> 5;
    const int rt2_s = (l >> 4) & 1;
    const int o_s = w * 2 + oo_s;
    const int r = rt2_s * 16 + (l & 15);
    const float v = oo_s ? (rt2_s ? p[1][1] : p[1][0]) : (rt2_s ? p[0][1] : p[0][0]);
    const int ra = __shfl(rid_o, r);
    if (ra >= 0) out[(size_t)ra * NO + o_s] = v + pb3[o_s * NT + t];
}

extern "C" void kernel_launch(void* const* d_in, const int* in_sizes, int n_in,
                              void* d_out, int out_size, void* d_ws, size_t ws_size,
                              hipStream_t stream) {
    const float* X   = (const float*)d_in[0];
    const int* trt   = (const int*)d_in[1];
    const float* W1  = (const float*)d_in[2];
    const float* b1  = (const float*)d_in[3];
    const float* g1  = (const float*)d_in[4];
    const float* be1 = (const float*)d_in[5];
    const float* m1  = (const float*)d_in[6];
    const float* v1  = (const float*)d_in[7];
    const float* W2  = (const float*)d_in[8];
    const float* b2  = (const float*)d_in[9];
    const float* g2  = (const float*)d_in[10];
    const float* be2 = (const float*)d_in[11];
    const float* m2  = (const float*)d_in[12];
    const float* v2  = (const float*)d_in[13];
    const float* W3  = (const float*)d_in[14];
    const float* b3  = (const float*)d_in[15];
    float* out = (float*)d_out;

    const int B = in_sizes[1];
    int* wsi   = (int*)d_ws;
    int* rperm = wsi + 16;
    int* iperm = rperm + (B + 128);
    char* wsb  = (char*)d_ws;
    size_t off = 64 + (size_t)(B + 128) * 4 + (size_t)B * 4;
    off = (off + 15) & ~(size_t)15;
    char* W1T = wsb + off;
    char* W2T = W1T + 1048576;
    float* P1 = (float*)(W2T + 131072);
    float* P2 = P1 + 6144;
    size_t endP = off + 1048576 + 131072 + 6144 * 4 + 3072 * 4;
    size_t offXs = (endP + 511) & ~(size_t)511;
    char* Xs = wsb + offXs;
    const size_t need = offXs + (size_t)(B + 128) * 512;
    const int useXs = (ws_size >= need) ? 1 : 0;

    hipMemsetAsync(wsi, 0, 64, stream);
    hipMemsetAsync(rperm, 0xFF, (size_t)(B + 128) * 4, stream);

    k_hist_prep<<<556, 256, 0, stream>>>(trt, wsi, B, W1, W2,
                                         b1, g1, be1, m1, v1,
                                         b2, g2, be2, m2, v2, W3,
                                         (unsigned*)W1T, (unsigned*)W2T, P1, P2);
    k_scatter<<<(B + 255) / 256, 256, 0, stream>>>(trt, wsi, rperm, iperm, B);
    if (useXs)
        k_xcopy<<<(B + 127) / 128, 256, 0, stream>>>(X, iperm, Xs, B);

    const int gx = (B + 128) / 32;                  // covers padded total
    k_main<<<gx, 256, 0, stream>>>(X, wsi, rperm, Xs, useXs,
                                   W1T, W2T, P1, P2, b3, out);
}

// Round 9
// 63.177 us; speedup vs baseline: 1.2213x; 1.2213x over previous
//
#include <hip/hip_runtime.h>
#include <cstdint>

typedef short bf16x8 __attribute__((ext_vector_type(8)));
typedef float f32x4 __attribute__((ext_vector_type(4)));

#define NO 8
#define NT 4
#define ND 256
#define NH1 64
#define NH2 32
#define BM 64
#define BNEPS 1e-5f

__device__ __forceinline__ unsigned bfpack2(float a, float b) {
    unsigned ua = __float_as_uint(a), ub = __float_as_uint(b);
    ua = (ua + 0x7FFFu + ((ua >> 16) & 1u)) >> 16;
    ub = (ub + 0x7FFFu + ((ub >> 16) & 1u)) >> 16;
    return ua | (ub << 16);
}

// ws layout (bytes):
//   [0,64): int cnt[4] @0, cursor[4] @16  (zeroed by memset)
//   rperm[B+256]: padded slot -> row id (-1 holes; memset 0xFF)
//   W1T (1 MB), W2T (128 KB), P1 (24 KB), P2 (12 KB)

__global__ void k_hist_prep(const int* __restrict__ trt, int* __restrict__ ws, int B,
                            const float* __restrict__ W1, const float* __restrict__ W2,
                            const float* __restrict__ b1, const float* __restrict__ g1,
                            const float* __restrict__ be1, const float* __restrict__ m1,
                            const float* __restrict__ v1,
                            const float* __restrict__ b2, const float* __restrict__ g2,
                            const float* __restrict__ be2, const float* __restrict__ m2,
                            const float* __restrict__ v2, const float* __restrict__ W3,
                            unsigned* __restrict__ W1T4, unsigned* __restrict__ W2T4,
                            float* __restrict__ P1, float* __restrict__ P2) {
    const int bid = blockIdx.x, tid = threadIdx.x;
    if (bid < 256) {                                      // ---- histogram ----
        __shared__ int loc[NT];
        if (tid < NT) loc[tid] = 0;
        __syncthreads();
        const int i = bid * 256 + tid;
        if (i < B) atomicAdd(&loc[trt[i] & 3], 1);
        __syncthreads();
        if (tid < NT) atomicAdd(&ws[tid], loc[tid]);
    } else if (bid < 512) {                               // ---- W1T frags ----
        const int gi = (bid - 256) * 256 + tid;           // 65536
        const int lane = gi & 63, nt = (gi >> 6) & 31, c = (gi >> 11) & 7, t = gi >> 14;
        const int n16 = lane & 15, kg = lane >> 4;
        const int n = nt * 16 + n16, o = n >> 6, h = n & 63;
        const int k0 = c * 32 + kg * 8;
        const float* src = W1 + ((size_t)(o * NT + t) * ND + k0) * NH1 + h;
        float v[8];
#pragma unroll
        for (int j = 0; j < 8; ++j) v[j] = src[(size_t)j * NH1];
        uint4 q;
        q.x = bfpack2(v[0], v[1]); q.y = bfpack2(v[2], v[3]);
        q.z = bfpack2(v[4], v[5]); q.w = bfpack2(v[6], v[7]);
        ((uint4*)W1T4)[gi] = q;
    } else if (bid < 544) {                               // ---- W2T frags ----
        const int gi = (bid - 512) * 256 + tid;           // 8192
        const int m16 = gi & 15, kg = (gi >> 4) & 3, ks = (gi >> 6) & 1,
                  kt = (gi >> 7) & 1, o = (gi >> 8) & 7, t = gi >> 11;
        const int k2 = kt * 16 + m16, hb = ks * 32 + kg * 8;
        const float* src = W2 + ((size_t)(o * NT + t) * NH1 + hb) * NH2 + k2;
        float v[8];
#pragma unroll
        for (int j = 0; j < 8; ++j) v[j] = src[(size_t)j * NH2];
        uint4 q;
        q.x = bfpack2(v[0], v[1]); q.y = bfpack2(v[2], v[3]);
        q.z = bfpack2(v[4], v[5]); q.w = bfpack2(v[6], v[7]);
        ((uint4*)W2T4)[gi] = q;
    } else if (bid < 552) {                               // ---- P1: BN1 fold ----
        const int gi = (bid - 544) * 256 + tid;           // 2048 = 4t x 512n
        const int t = gi >> 9, n = gi & 511;
        const int o = n >> 6, h = n & 63;
        const int idx = (o * NT + t) * NH1 + h;
        const float sc = g1[idx] * rsqrtf(v1[idx] + BNEPS);
        P1[gi] = sc;
        P1[2048 + gi] = be1[idx] - m1[idx] * sc;
        P1[4096 + gi] = b1[idx];
    } else {                                              // ---- P2: BN2+W3 fold ----
        const int gi = (bid - 552) * 256 + tid;           // 1024 = 4t x 256(o,k2)
        const int t = gi >> 8, q = gi & 255;
        const int o = q >> 5, k2 = q & 31;
        const int idx = (o * NT + t) * NH2 + k2;
        const float s = g2[idx] * rsqrtf(v2[idx] + BNEPS);
        const float w3 = W3[idx];
        P2[gi] = s * w3;
        P2[1024 + gi] = (be2[idx] - m2[idx] * s) * w3;
        P2[2048 + gi] = b2[idx];
    }
}

__global__ void k_scatter(const int* __restrict__ trt, int* __restrict__ ws,
                          int* __restrict__ rperm, int B) {
    __shared__ int loc[NT], gb[NT];
    const int tid = threadIdx.x;
    if (tid < NT) loc[tid] = 0;
    __syncthreads();
    const int i = blockIdx.x * blockDim.x + tid;
    int tt = 0, pos = 0;
    if (i < B) { tt = trt[i] & 3; pos = atomicAdd(&loc[tt], 1); }
    __syncthreads();
    if (tid < NT) {
        const int c0 = ws[0], c1 = ws[1], c2 = ws[2];
        const int q0 = (c0 + 63) & ~63, q1 = (c1 + 63) & ~63, q2 = (c2 + 63) & ~63;
        const int eb = tid == 0 ? 0 : tid == 1 ? q0 : tid == 2 ? q0 + q1 : q0 + q1 + q2;
        gb[tid] = eb + atomicAdd(&ws[4 + tid], loc[tid]);
    }
    __syncthreads();
    if (i < B) rperm[gb[tt] + pos] = i;
}

// ---------------- fused 3-layer expert MLP: 64-row blocks, 8 waves ----------------
// wave w: L1 cols (w*4..w*4+3) n-frags x 4 row-frags (acc 64 AGPR); layer2 outcome o=w.
__global__ __launch_bounds__(512, 2) void k_main(
    const float* __restrict__ X, const int* __restrict__ ws, const int* __restrict__ rperm,
    const char* __restrict__ W1T, const char* __restrict__ W2T,
    const float* __restrict__ P1, const float* __restrict__ P2,
    const float* __restrict__ pb3, float* __restrict__ out)
{
    const int c0 = ws[0], c1 = ws[1], c2 = ws[2], c3 = ws[3];
    const int q0 = (c0 + 63) & ~63, q1 = (c1 + 63) & ~63, q2 = (c2 + 63) & ~63;
    const int e0 = q0, e1 = q0 + q1, e2 = e1 + q2, e3 = e2 + ((c3 + 63) & ~63);
    const int m0 = blockIdx.x * BM;
    if (m0 >= e3) return;
    const int t = (m0 >= e0) + (m0 >= e1) + (m0 >= e2);

    const int tid = threadIdx.x;
    const int w = tid >> 6;          // 0..7
    const int l = tid & 63;

    // [0,32768): X tile [64 r][512 B] bf16 swizzled; after K-loop: Hr [64 r][1024 B]
    __shared__ __align__(16) char LDS[65536];

    const int rid_l = rperm[m0 + l];     // padded slot -> row (-1 = hole)

    // ---- stage X: each wave gathers 8 rows, 1 KB coalesced each ----
#pragma unroll
    for (int j = 0; j < 8; ++j) {
        const int r = w * 8 + j;
        const int rr = __shfl(rid_l, r);
        const int rrow = rr < 0 ? 0 : rr;
        const float4 xv = *(const float4*)(X + (size_t)rrow * ND + l * 4);
        uint2 pk;
        pk.x = bfpack2(xv.x, xv.y);
        pk.y = bfpack2(xv.z, xv.w);
        *(uint2*)(LDS + r * 512 + ((l * 8) ^ ((r & 7) << 4))) = pk;
    }

    f32x4 acc[4][4];                 // [jn][rt]
#pragma unroll
    for (int jn = 0; jn < 4; ++jn)
#pragma unroll
        for (int rt = 0; rt < 4; ++rt) acc[jn][rt] = (f32x4){0.f, 0.f, 0.f, 0.f};

    const char* W1Tw = W1T + (size_t)t * 262144 + (w * 4) * 1024 + l * 16;
    const int ln4 = (l >> 4) * 4;

    __syncthreads();

    // ---- K-loop: 4 W frags/wave/chunk from L2, X frags from LDS ----
#pragma unroll
    for (int c = 0; c < 8; ++c) {
        bf16x8 aA[4];
#pragma unroll
        for (int jn = 0; jn < 4; ++jn)
            aA[jn] = *(const bf16x8*)(W1Tw + c * 32768 + jn * 1024);
#pragma unroll
        for (int rt = 0; rt < 4; ++rt) {
            const int r = rt * 16 + (l & 15);
            const bf16x8 bX = *(const bf16x8*)(LDS + r * 512 +
                                               ((c * 64 + (l >> 4) * 16) ^ ((r & 7) << 4)));
#pragma unroll
            for (int jn = 0; jn < 4; ++jn)
                acc[jn][rt] = __builtin_amdgcn_mfma_f32_16x16x32_bf16(aA[jn], bX, acc[jn][rt], 0, 0, 0);
        }
    }
    __syncthreads();     // X reads done; LDS becomes Hr

    // ---- epilogue L1: bias+ReLU+BN1 (pre-folded), bf16 swizzled Hr[r][n] ----
#pragma unroll
    for (int jn = 0; jn < 4; ++jn) {
        const int n0 = (w * 4 + jn) * 16 + ln4;
        const int p = t * 512 + n0;
        const float4 scv = *(const float4*)(P1 + p);
        const float4 shv = *(const float4*)(P1 + 2048 + p);
        const float4 bbv = *(const float4*)(P1 + 4096 + p);
#pragma unroll
        for (int rt = 0; rt < 4; ++rt) {
            const int r = rt * 16 + (l & 15);
            const f32x4 a = acc[jn][rt];
            const float z0 = fmaf(fmaxf(a[0] + bbv.x, 0.f), scv.x, shv.x);
            const float z1 = fmaf(fmaxf(a[1] + bbv.y, 0.f), scv.y, shv.y);
            const float z2 = fmaf(fmaxf(a[2] + bbv.z, 0.f), scv.z, shv.z);
            const float z3 = fmaf(fmaxf(a[3] + bbv.w, 0.f), scv.w, shv.w);
            uint2 pk;
            pk.x = bfpack2(z0, z1); pk.y = bfpack2(z2, z3);
            *(uint2*)(LDS + r * 1024 + (((unsigned)(n0 * 2)) ^ (unsigned)((r & 7) << 4))) = pk;
        }
    }
    // wave w wrote cols [w*64, w*64+64) and layer2 (o=w) reads exactly those -> no barrier

    // ---- layer 2: MFMA, outcome o = w ----
    bf16x8 aW[2][2];     // [kt][ks]
#pragma unroll
    for (int kt = 0; kt < 2; ++kt)
#pragma unroll
        for (int ks = 0; ks < 2; ++ks)
            aW[kt][ks] = *(const bf16x8*)(W2T +
                ((((size_t)t * NO + w) * 2 + kt) * 2 + ks) * 1024 + l * 16);

    f32x4 acc2[2][4];    // [kt][rt2]
#pragma unroll
    for (int kt = 0; kt < 2; ++kt)
#pragma unroll
        for (int rt2 = 0; rt2 < 4; ++rt2) acc2[kt][rt2] = (f32x4){0.f, 0.f, 0.f, 0.f};

#pragma unroll
    for (int rt2 = 0; rt2 < 4; ++rt2) {
        const int r = rt2 * 16 + (l & 15);
        const unsigned swz = (unsigned)((r & 7) << 4);
#pragma unroll
        for (int ks = 0; ks < 2; ++ks) {
            const int n8 = w * 64 + ks * 32 + (l >> 4) * 8;
            const bf16x8 bH = *(const bf16x8*)(LDS + r * 1024 + (((unsigned)(n8 * 2)) ^ swz));
#pragma unroll
            for (int kt = 0; kt < 2; ++kt)
                acc2[kt][rt2] = __builtin_amdgcn_mfma_f32_16x16x32_bf16(aW[kt][ks], bH, acc2[kt][rt2], 0, 0, 0);
        }
    }

    // ---- BN2 + ReLU + layer3 dot (pre-folded), reduce over k-lane-groups ----
    float pr[4];
#pragma unroll
    for (int rt2 = 0; rt2 < 4; ++rt2) pr[rt2] = 0.f;

#pragma unroll
    for (int kt = 0; kt < 2; ++kt) {
        const int q3 = w * 32 + kt * 16 + ln4;
        const int p3 = t * 256 + q3;
        const float4 A3 = *(const float4*)(P2 + p3);
        const float4 C3 = *(const float4*)(P2 + 1024 + p3);
        const float4 bb = *(const float4*)(P2 + 2048 + p3);
#pragma unroll
        for (int rt2 = 0; rt2 < 4; ++rt2) {
            const f32x4 a = acc2[kt][rt2];
            float s = fmaf(fmaxf(a[0] + bb.x, 0.f), A3.x, C3.x);
            s = fmaf(fmaxf(a[1] + bb.y, 0.f), A3.y, s + C3.y);
            s = fmaf(fmaxf(a[2] + bb.z, 0.f), A3.z, s + C3.z);
            s = fmaf(fmaxf(a[3] + bb.w, 0.f), A3.w, s + C3.w);
            pr[rt2] += s;
        }
    }
#pragma unroll
    for (int rt2 = 0; rt2 < 4; ++rt2) {
        float v = pr[rt2];
        v += __shfl_xor(v, 16);
        v += __shfl_xor(v, 32);
        pr[rt2] = v;
    }

    // lane l writes row r = l (rt2 = l>>4, within-frag col = l&15)
    const int sel = l >> 4;
    const float v = sel == 0 ? pr[0] : sel == 1 ? pr[1] : sel == 2 ? pr[2] : pr[3];
    if (rid_l >= 0) out[(size_t)rid_l * NO + w] = v + pb3[w * NT + t];
}

extern "C" void kernel_launch(void* const* d_in, const int* in_sizes, int n_in,
                              void* d_out, int out_size, void* d_ws, size_t ws_size,
                              hipStream_t stream) {
    const float* X   = (const float*)d_in[0];
    const int* trt   = (const int*)d_in[1];
    const float* W1  = (const float*)d_in[2];
    const float* b1  = (const float*)d_in[3];
    const float* g1  = (const float*)d_in[4];
    const float* be1 = (const float*)d_in[5];
    const float* m1  = (const float*)d_in[6];
    const float* v1  = (const float*)d_in[7];
    const float* W2  = (const float*)d_in[8];
    const float* b2  = (const float*)d_in[9];
    const float* g2  = (const float*)d_in[10];
    const float* be2 = (const float*)d_in[11];
    const float* m2  = (const float*)d_in[12];
    const float* v2  = (const float*)d_in[13];
    const float* W3  = (const float*)d_in[14];
    const float* b3  = (const float*)d_in[15];
    float* out = (float*)d_out;

    const int B = in_sizes[1];
    const int permCap = B + 4 * BM;
    int* wsi   = (int*)d_ws;
    int* rperm = wsi + 16;
    char* wsb  = (char*)d_ws;
    size_t off = (64 + (size_t)permCap * 4 + 15) & ~(size_t)15;
    char* W1T = wsb + off;
    char* W2T = W1T + 1048576;
    float* P1 = (float*)(W2T + 131072);
    float* P2 = P1 + 6144;

    hipMemsetAsync(wsi, 0, 64, stream);
    hipMemsetAsync(rperm, 0xFF, (size_t)permCap * 4, stream);

    k_hist_prep<<<556, 256, 0, stream>>>(trt, wsi, B, W1, W2,
                                         b1, g1, be1, m1, v1,
                                         b2, g2, be2, m2, v2, W3,
                                         (unsigned*)W1T, (unsigned*)W2T, P1, P2);
    k_scatter<<<(B + 255) / 256, 256, 0, stream>>>(trt, wsi, rperm, B);

    const int gx = (B + 63) / 64 + 4;               // covers padded buckets
    k_main<<<gx, 512, 0, stream>>>(X, wsi, rperm, W1T, W2T, P1, P2, b3, out);
}